// Round 1
// baseline (1629.333 us; speedup 1.0000x reference)
//
#include <hip/hip_runtime.h>
#include <hip/hip_bf16.h>

// Problem constants (QREncoder: path signature depth 4 + linear head)
#define BATCH 64
#define LSEQ 256
#define CIN 7
#define CC 8           // channels incl. time
#define NSIG 4680      // 8 + 64 + 512 + 4096
#define KPAD 4736      // NSIG padded to multiple of 64
#define TSTEPS 255     // LSEQ - 1
#define ODIM 512
#define M_TOTAL (BATCH * TSTEPS)   // 16320 = 255 * 64 exactly

typedef __attribute__((ext_vector_type(8))) unsigned short ushort8;

__device__ __forceinline__ float bflo(unsigned int u) {
    union { unsigned int i; float f; } c; c.i = u << 16; return c.f;
}
__device__ __forceinline__ float bfhi(unsigned int u) {
    union { unsigned int i; float f; } c; c.i = u & 0xffff0000u; return c.f;
}
__device__ __forceinline__ unsigned short f2bf(float x) {
    __hip_bfloat16 h = __float2bfloat16(x);   // RNE
    return *(unsigned short*)&h;
}

// ---------------------------------------------------------------------------
// Phase 1: signature scan. One block per batch path, 512 threads.
// Thread tid owns a3[tid] (register) and a4[8*tid .. 8*tid+8) (registers).
// a1 (8) + a2 (64) live in LDS, double-buffered -> 1 barrier per step.
// Writes each step's full signature row (bf16, KPAD wide, zero pad cols).
// ---------------------------------------------------------------------------
__global__ __launch_bounds__(512) void sig_kernel(const float* __restrict__ inp,
                                                  unsigned short* __restrict__ sig) {
    __shared__ float sDx[TSTEPS * CC];   // 2040 floats: per-step increments
    __shared__ float sA12[2][72];        // [buf][ a1(8) | a2(64) ]

    const int b   = blockIdx.x;
    const int tid = threadIdx.x;

    // Build dx: dx[t][0] = 1/255 (time channel), dx[t][c] = inp[t+1,c-1]-inp[t,c-1]
    const float* ip = inp + (size_t)b * LSEQ * CIN;
    for (int i = tid; i < TSTEPS * CC; i += 512) {
        int t = i >> 3, c = i & 7;
        sDx[i] = (c == 0) ? (1.0f / 255.0f)
                          : ip[(t + 1) * CIN + (c - 1)] - ip[t * CIN + (c - 1)];
    }
    for (int i = tid; i < 144; i += 512) ((float*)sA12)[i] = 0.0f;

    float a3 = 0.0f;
    float a4[8];
#pragma unroll
    for (int e = 0; e < 8; ++e) a4[e] = 0.0f;

    __syncthreads();

    const int i1 = tid >> 6;         // leading index (0..7)
    const int i2 = (tid >> 3) & 7;
    const int i3 = tid & 7;

    int cur = 0;
    for (int t = 0; t < TSTEPS; ++t) {
        const float* v = &sDx[t * CC];
        float vv[8];
#pragma unroll
        for (int e = 0; e < 8; ++e) vv[e] = v[e];
        const float va = v[i1], vb = v[i2], vc = v[i3];
        const float a1b = sA12[cur][i1];            // a1[i1]
        const float a2b = sA12[cur][8 + (tid >> 3)];// a2[i1*8+i2]

        const float e3s = va * vb * vc * (1.0f / 6.0f);
        // level-3 update (thread owns a3[tid])
        const float na3 = a3 + e3s + (a1b * vb * 0.5f + a2b) * vc;
        // level-4 common factor: new4[e] = a4[e] + v[e]*T4
        const float T4 = e3s * 0.25f
                       + a1b * vb * vc * (1.0f / 6.0f)
                       + a2b * vc * 0.5f
                       + a3;
        float na4[8];
#pragma unroll
        for (int e = 0; e < 8; ++e) na4[e] = a4[e] + vv[e] * T4;

        // level-1 / level-2 owners (threads 0..71)
        float na12 = 0.0f;
        if (tid < 72) {
            if (tid < 8) {
                na12 = sA12[cur][tid] + v[tid];
            } else {
                int q = tid - 8;                    // a2 index
                na12 = sA12[cur][tid] + v[q & 7] * (0.5f * v[q >> 3] + sA12[cur][q >> 3]);
            }
        }

        // ---- write signature row (bf16) ----
        unsigned short* row = sig + ((size_t)b * TSTEPS + t) * KPAD;
        ushort8 pack;
#pragma unroll
        for (int e = 0; e < 8; ++e) pack[e] = f2bf(na4[e]);
        *(ushort8*)(row + 584 + tid * 8) = pack;    // level 4: [584, 4680)
        row[72 + tid] = f2bf(na3);                  // level 3: [72, 584)
        if (tid < 72) row[tid] = f2bf(na12);        // levels 1-2: [0, 72)
        if (tid >= 448 && tid < 504) row[4232 + tid] = 0;   // pad [4680, 4736)

        // ---- commit state ----
        a3 = na3;
#pragma unroll
        for (int e = 0; e < 8; ++e) a4[e] = na4[e];
        const int nxt = cur ^ 1;
        if (tid < 72) sA12[nxt][tid] = na12;
        __syncthreads();
        cur = nxt;
    }
}

// ---------------------------------------------------------------------------
// Phase 2: out[m][n] = sum_k sig[m][k] * W[n][k] + bias[n]
// A: bf16 [Mrows][KPAD], W: fp32 [512][4680]. 64x64 tile, 256 thr, 4x4/thread.
// LDS pads chosen so all inner reads are <=2-way bank conflicts (free).
// ---------------------------------------------------------------------------
__global__ __launch_bounds__(256) void gemm_kernel(const unsigned short* __restrict__ A,
                                                   const float* __restrict__ W,
                                                   const float* __restrict__ bias,
                                                   float* __restrict__ out,
                                                   int Mrows) {
    __shared__ unsigned short As[64][66];   // row stride 132B = 33 banks
    __shared__ float Bs[64][65];            // row stride 260B -> stride 1 bank per row

    const int tid = threadIdx.x;
    const int nt = blockIdx.x, mt = blockIdx.y;
    const int tx = tid & 15, ty = tid >> 4;

    float acc[4][4];
#pragma unroll
    for (int i = 0; i < 4; ++i)
#pragma unroll
        for (int j = 0; j < 4; ++j) acc[i][j] = 0.0f;

    const int arow = tid >> 3;            // 0..31 (two passes)
    const int acol = (tid & 7) * 8;       // ushort8 per thread
    const int brow = tid >> 2;            // 0..63
    const int bcol4 = (tid & 3) * 4;      // float4 per thread, 4 passes

    for (int k0 = 0; k0 < KPAD; k0 += 64) {
        // stage A (bf16)
#pragma unroll
        for (int rr = 0; rr < 64; rr += 32) {
            int gr = mt * 64 + arow + rr;
            if (gr >= Mrows) gr = Mrows - 1;   // clamp (dup row, outputs guarded)
            union { ushort8 v; unsigned int u[4]; } av;
            av.v = *(const ushort8*)(A + (size_t)gr * KPAD + k0 + acol);
#pragma unroll
            for (int e = 0; e < 4; ++e)
                *(unsigned int*)&As[arow + rr][acol + e * 2] = av.u[e];
        }
        // stage B (fp32 W), K-tail guarded (only last tile: k0=4672)
        const int gn = nt * 64 + brow;
        if (k0 + 64 <= NSIG) {
#pragma unroll
            for (int cc = 0; cc < 4; ++cc) {
                float4 bv = *(const float4*)(W + (size_t)gn * NSIG + k0 + bcol4 + cc * 16);
                Bs[brow][bcol4 + cc * 16 + 0] = bv.x;
                Bs[brow][bcol4 + cc * 16 + 1] = bv.y;
                Bs[brow][bcol4 + cc * 16 + 2] = bv.z;
                Bs[brow][bcol4 + cc * 16 + 3] = bv.w;
            }
        } else {
#pragma unroll
            for (int cc = 0; cc < 4; ++cc)
                for (int e = 0; e < 4; ++e) {
                    int k = k0 + bcol4 + cc * 16 + e;
                    Bs[brow][bcol4 + cc * 16 + e] =
                        (k < NSIG) ? W[(size_t)gn * NSIG + k] : 0.0f;
                }
        }
        __syncthreads();

#pragma unroll 8
        for (int kk = 0; kk < 64; kk += 2) {
            unsigned int ap[4];
            float b0[4], b1[4];
#pragma unroll
            for (int i = 0; i < 4; ++i)
                ap[i] = *(const unsigned int*)&As[ty * 4 + i][kk];
#pragma unroll
            for (int j = 0; j < 4; ++j) {
                b0[j] = Bs[tx * 4 + j][kk];
                b1[j] = Bs[tx * 4 + j][kk + 1];
            }
#pragma unroll
            for (int i = 0; i < 4; ++i)
#pragma unroll
                for (int j = 0; j < 4; ++j)
                    acc[i][j] += bflo(ap[i]) * b0[j] + bfhi(ap[i]) * b1[j];
        }
        __syncthreads();
    }

#pragma unroll
    for (int i = 0; i < 4; ++i) {
        const int m = mt * 64 + ty * 4 + i;
        if (m < Mrows) {
#pragma unroll
            for (int j = 0; j < 4; ++j) {
                const int n = nt * 64 + tx * 4 + j;
                out[(size_t)m * ODIM + n] = acc[i][j] + bias[n];
            }
        }
    }
}

extern "C" void kernel_launch(void* const* d_in, const int* in_sizes, int n_in,
                              void* d_out, int out_size, void* d_ws, size_t ws_size,
                              hipStream_t stream) {
    const float* inp  = (const float*)d_in[0];
    const float* W    = (const float*)d_in[1];
    const float* bias = (const float*)d_in[2];
    float* out = (float*)d_out;
    unsigned short* sig = (unsigned short*)d_ws;

    // Chunk over batch if workspace is too small for all 155 MB of signatures.
    const size_t perBatch = (size_t)TSTEPS * KPAD * sizeof(unsigned short);
    int nbMax = (int)(ws_size / perBatch);
    if (nbMax > BATCH) nbMax = BATCH;
    if (nbMax < 1) nbMax = 1;

    for (int b0 = 0; b0 < BATCH; b0 += nbMax) {
        const int nb = (b0 + nbMax <= BATCH) ? nbMax : (BATCH - b0);
        const int Mrows = nb * TSTEPS;
        sig_kernel<<<nb, 512, 0, stream>>>(inp + (size_t)b0 * LSEQ * CIN, sig);
        gemm_kernel<<<dim3(ODIM / 64, (Mrows + 63) / 64), 256, 0, stream>>>(
            sig, W, bias, out + (size_t)b0 * TSTEPS * ODIM, Mrows);
    }
}

// Round 2
// 215.494 us; speedup vs baseline: 7.5609x; 7.5609x over previous
//
#include <hip/hip_runtime.h>
#include <hip/hip_bf16.h>

// Problem constants (QREncoder: path signature depth 4 + linear head)
#define BATCH 64
#define LSEQ 256
#define CIN 7
#define CC 8           // channels incl. time
#define NSIG 4680      // 8 + 64 + 512 + 4096
#define KPAD 4736      // NSIG padded to multiple of 64
#define TSTEPS 255     // LSEQ - 1
#define ODIM 512
#define M_TOTAL (BATCH * TSTEPS)   // 16320

typedef __attribute__((ext_vector_type(8))) unsigned short ushort8;
typedef __attribute__((ext_vector_type(8))) __bf16 bf16x8;
typedef __attribute__((ext_vector_type(4))) float f32x4;

__device__ __forceinline__ unsigned short f2bf(float x) {
    __hip_bfloat16 h = __float2bfloat16(x);   // RNE
    return *(unsigned short*)&h;
}

#define GLDS16(gp, lp)                                                      \
    __builtin_amdgcn_global_load_lds(                                       \
        (const __attribute__((address_space(1))) void*)(gp),                \
        (__attribute__((address_space(3))) void*)(lp), 16, 0, 0)

// ---------------------------------------------------------------------------
// Phase 1: signature scan. One block per batch path, 512 threads.
// Thread tid owns a3[tid] (register) and a4[8*tid..+8) (registers).
// a1(8)+a2(64) in LDS, double-buffered -> 1 barrier per step.
// ---------------------------------------------------------------------------
__global__ __launch_bounds__(512) void sig_kernel(const float* __restrict__ inp,
                                                  unsigned short* __restrict__ sig) {
    __shared__ float sDx[TSTEPS * CC];
    __shared__ float sA12[2][72];

    const int b   = blockIdx.x;
    const int tid = threadIdx.x;

    const float* ip = inp + (size_t)b * LSEQ * CIN;
    for (int i = tid; i < TSTEPS * CC; i += 512) {
        int t = i >> 3, c = i & 7;
        sDx[i] = (c == 0) ? (1.0f / 255.0f)
                          : ip[(t + 1) * CIN + (c - 1)] - ip[t * CIN + (c - 1)];
    }
    for (int i = tid; i < 144; i += 512) ((float*)sA12)[i] = 0.0f;

    float a3 = 0.0f;
    float a4[8];
#pragma unroll
    for (int e = 0; e < 8; ++e) a4[e] = 0.0f;

    __syncthreads();

    const int i1 = tid >> 6;
    const int i2 = (tid >> 3) & 7;
    const int i3 = tid & 7;

    int cur = 0;
    for (int t = 0; t < TSTEPS; ++t) {
        const float* v = &sDx[t * CC];
        float vv[8];
#pragma unroll
        for (int e = 0; e < 8; ++e) vv[e] = v[e];
        const float va = v[i1], vb = v[i2], vc = v[i3];
        const float a1b = sA12[cur][i1];
        const float a2b = sA12[cur][8 + (tid >> 3)];

        const float e3s = va * vb * vc * (1.0f / 6.0f);
        const float na3 = a3 + e3s + (a1b * vb * 0.5f + a2b) * vc;
        const float T4 = e3s * 0.25f
                       + a1b * vb * vc * (1.0f / 6.0f)
                       + a2b * vc * 0.5f
                       + a3;
        float na4[8];
#pragma unroll
        for (int e = 0; e < 8; ++e) na4[e] = a4[e] + vv[e] * T4;

        float na12 = 0.0f;
        if (tid < 72) {
            if (tid < 8) {
                na12 = sA12[cur][tid] + v[tid];
            } else {
                int q = tid - 8;
                na12 = sA12[cur][tid] + v[q & 7] * (0.5f * v[q >> 3] + sA12[cur][q >> 3]);
            }
        }

        unsigned short* row = sig + ((size_t)b * TSTEPS + t) * KPAD;
        ushort8 pack;
#pragma unroll
        for (int e = 0; e < 8; ++e) pack[e] = f2bf(na4[e]);
        *(ushort8*)(row + 584 + tid * 8) = pack;
        row[72 + tid] = f2bf(na3);
        if (tid < 72) row[tid] = f2bf(na12);
        if (tid >= 448 && tid < 504) row[4232 + tid] = 0;

        a3 = na3;
#pragma unroll
        for (int e = 0; e < 8; ++e) a4[e] = na4[e];
        const int nxt = cur ^ 1;
        if (tid < 72) sA12[nxt][tid] = na12;
        __syncthreads();
        cur = nxt;
    }
}

// ---------------------------------------------------------------------------
// W fp32 [512][4680] -> bf16 [512][KPAD] (pad zeroed)
// ---------------------------------------------------------------------------
__global__ __launch_bounds__(256) void wcvt_kernel(const float* __restrict__ W,
                                                   unsigned short* __restrict__ Wb) {
    int idx = blockIdx.x * 256 + threadIdx.x;
    if (idx >= ODIM * KPAD) return;
    int n = idx / KPAD, k = idx - n * KPAD;
    Wb[idx] = (k < NSIG) ? f2bf(W[(size_t)n * NSIG + k]) : (unsigned short)0;
}

// ---------------------------------------------------------------------------
// Phase 2: MFMA GEMM. out[m][n] = sum_k A[m][k]*Wb[n][k] + bias[n]
// A bf16 [Mrows][KPAD], Wb bf16 [512][KPAD]. 128x128 tile, BK=64, 4 waves,
// each wave 64x64 (4x4 frags of 16x16x32 bf16). global_load_lds width 16.
// blockIdx.x = n-tile (0..3), blockIdx.y = m-tile.
// ---------------------------------------------------------------------------
__global__ __launch_bounds__(256) void gemm_kernel(const unsigned short* __restrict__ A,
                                                   const unsigned short* __restrict__ Wb,
                                                   const float* __restrict__ bias,
                                                   float* __restrict__ out,
                                                   int Mrows) {
    __shared__ unsigned short As[128 * 64];   // 16 KB
    __shared__ unsigned short Bs[128 * 64];   // 16 KB

    const int tid  = threadIdx.x;
    const int nt   = blockIdx.x;
    const int mt   = blockIdx.y;
    const int lane = tid & 63;
    const int wv   = tid >> 6;            // 0..3
    const int wr   = wv >> 1;             // wave row (0..1)
    const int wc   = wv & 1;              // wave col (0..1)
    const int lr   = lane & 15;           // frag row (A) / col (B,D)
    const int lk   = (lane >> 4) * 8;     // k offset within 32

    const f32x4 z = {0.0f, 0.0f, 0.0f, 0.0f};
    f32x4 acc[4][4];
#pragma unroll
    for (int i = 0; i < 4; ++i)
#pragma unroll
        for (int j = 0; j < 4; ++j) acc[i][j] = z;

    const int srow = tid >> 3;            // 0..31
    const int scol = (tid & 7) * 8;       // element offset within BK

    for (int k0 = 0; k0 < KPAD; k0 += 64) {
        // stage A+B: 4 issues each, 16 B/lane, LDS dest linear in tid
#pragma unroll
        for (int i = 0; i < 4; ++i) {
            int gr = mt * 128 + i * 32 + srow;
            if (gr >= Mrows) gr = 0;       // clamp to a valid row; stores guarded
            GLDS16(A + (size_t)gr * KPAD + k0 + scol,
                   ((char*)As) + i * 4096 + tid * 16);
            const int gn = nt * 128 + i * 32 + srow;    // N=512 exact
            GLDS16(Wb + (size_t)gn * KPAD + k0 + scol,
                   ((char*)Bs) + i * 4096 + tid * 16);
        }
        __syncthreads();

#pragma unroll
        for (int ks = 0; ks < 2; ++ks) {
            const int kk = ks * 32 + lk;
            bf16x8 af[4], bf[4];
#pragma unroll
            for (int i = 0; i < 4; ++i)
                af[i] = *(const bf16x8*)&As[(wr * 64 + i * 16 + lr) * 64 + kk];
#pragma unroll
            for (int j = 0; j < 4; ++j)
                bf[j] = *(const bf16x8*)&Bs[(wc * 64 + j * 16 + lr) * 64 + kk];
#pragma unroll
            for (int i = 0; i < 4; ++i)
#pragma unroll
                for (int j = 0; j < 4; ++j)
                    acc[i][j] = __builtin_amdgcn_mfma_f32_16x16x32_bf16(
                        af[i], bf[j], acc[i][j], 0, 0, 0);
        }
        __syncthreads();
    }

    // epilogue: D col = lane&15, row = (lane>>4)*4 + r
    float bn[4];
#pragma unroll
    for (int j = 0; j < 4; ++j)
        bn[j] = bias[nt * 128 + wc * 64 + j * 16 + lr];

#pragma unroll
    for (int i = 0; i < 4; ++i) {
        const int mbase = mt * 128 + wr * 64 + i * 16 + (lane >> 4) * 4;
#pragma unroll
        for (int r = 0; r < 4; ++r) {
            const int m = mbase + r;
            if (m < Mrows) {
#pragma unroll
                for (int j = 0; j < 4; ++j) {
                    const int n = nt * 128 + wc * 64 + j * 16 + lr;
                    out[(size_t)m * ODIM + n] = acc[i][j][r] + bn[j];
                }
            }
        }
    }
}

extern "C" void kernel_launch(void* const* d_in, const int* in_sizes, int n_in,
                              void* d_out, int out_size, void* d_ws, size_t ws_size,
                              hipStream_t stream) {
    const float* inp  = (const float*)d_in[0];
    const float* W    = (const float*)d_in[1];
    const float* bias = (const float*)d_in[2];
    float* out = (float*)d_out;

    const size_t wbBytes  = (size_t)ODIM * KPAD * sizeof(unsigned short);
    const size_t perBatch = (size_t)TSTEPS * KPAD * sizeof(unsigned short);

    unsigned short* sig = (unsigned short*)d_ws;
    unsigned short* Wb  = (unsigned short*)((char*)d_ws + (ws_size - wbBytes));

    int nbMax = (int)((ws_size - wbBytes) / perBatch);
    if (nbMax > BATCH) nbMax = BATCH;
    if (nbMax < 1) nbMax = 1;

    wcvt_kernel<<<(ODIM * KPAD + 255) / 256, 256, 0, stream>>>(W, Wb);

    for (int b0 = 0; b0 < BATCH; b0 += nbMax) {
        const int nb = (b0 + nbMax <= BATCH) ? nbMax : (BATCH - b0);
        const int Mrows = nb * TSTEPS;
        sig_kernel<<<nb, 512, 0, stream>>>(inp + (size_t)b0 * LSEQ * CIN, sig);
        gemm_kernel<<<dim3(ODIM / 128, (Mrows + 127) / 128), 256, 0, stream>>>(
            sig, Wb, bias, out + (size_t)b0 * TSTEPS * ODIM, Mrows);
    }
}